// Round 1
// baseline (389.682 us; speedup 1.0000x reference)
//
#include <hip/hip_runtime.h>
#include <math.h>

// Problem constants
#define BB 8
#define HH 256
#define WWW 256
#define CC 32
#define CKK 4
#define NM 12     // M1 = M2 = 12
#define NMODE 24  // rows kept: 0..11 and 244..255

__device__ __forceinline__ float gelu_f(float v) {
    // jax.nn.gelu default: tanh approximation
    float u = 0.7978845608028654f * (v + 0.044715f * v * v * v);
    float e = __expf(2.0f * u);
    float t = 1.0f - 2.0f / (e + 1.0f);
    return 0.5f * v * (1.0f + t);
}

// -------- Kernel A: per-pixel v = L*u + Ms, fused row-DFT over w --------
// grid: B*H blocks, 256 threads (one per w)
// Writes A1[b][j][h][c][2] : row-DFT of v, 12 cols modes, complex.
__global__ __launch_bounds__(256) void kernA(
    const float* __restrict__ x, const float* __restrict__ kk,
    const float* __restrict__ Lw1, const float* __restrict__ Lb1,
    const float* __restrict__ Lw2, const float* __restrict__ Lb2,
    const float* __restrict__ uw,  const float* __restrict__ ub,
    const float* __restrict__ Msw, const float* __restrict__ Msb,
    float* __restrict__ A1)
{
    __shared__ float vbuf[256 * 33];   // [w][c] padded
    __shared__ float part[256 * 25];   // [thread][24 partials] padded

    const int bh = blockIdx.x;
    const int b  = bh >> 8;
    const int h  = bh & 255;
    const int w  = threadIdx.x;

    float kv[4];
    {
        const float4 t4 = *reinterpret_cast<const float4*>(kk + ((size_t)bh * 256 + w) * 4);
        kv[0] = t4.x; kv[1] = t4.y; kv[2] = t4.z; kv[3] = t4.w;
    }
    float xv[32];
    {
        const float4* xp = reinterpret_cast<const float4*>(x + ((size_t)bh * 256 + w) * 32);
        #pragma unroll
        for (int i = 0; i < 8; i++) {
            float4 t4 = xp[i];
            xv[4*i] = t4.x; xv[4*i+1] = t4.y; xv[4*i+2] = t4.z; xv[4*i+3] = t4.w;
        }
    }

    // L = gelu(k@Lw1+Lb1)@Lw2+Lb2 ; u = x@uw+ub ; Ms = k@Msw+Msb ; v = L*u+Ms
    float hb[64];
    #pragma unroll
    for (int m = 0; m < 64; m++) {
        float a = Lb1[m] + kv[0]*Lw1[m] + kv[1]*Lw1[64+m] + kv[2]*Lw1[128+m] + kv[3]*Lw1[192+m];
        hb[m] = gelu_f(a);
    }
    #pragma unroll 4
    for (int o = 0; o < 32; o++) {
        float L = Lb2[o];
        #pragma unroll
        for (int m = 0; m < 64; m++) L += hb[m] * Lw2[m*32 + o];
        float uu = ub[o];
        #pragma unroll
        for (int c = 0; c < 32; c++) uu += xv[c] * uw[c*32 + o];
        float ms = Msb[o] + kv[0]*Msw[o] + kv[1]*Msw[32+o] + kv[2]*Msw[64+o] + kv[3]*Msw[96+o];
        vbuf[w*33 + o] = L * uu + ms;
    }
    __syncthreads();

    // Phase 2: row-DFT. thread (c = w&31, chunk = w>>5) accumulates 32 w's.
    const int c     = w & 31;
    const int chunk = w >> 5;
    const float TP256 = 0.0245436926066f; // 2*pi/256

    float ebs, ebc; __sincosf(TP256 * (float)(chunk * 32), &ebs, &ebc);
    float d1s, d1c; __sincosf(TP256, &d1s, &d1c);
    float ec[11], es[11], dc[11], ds[11];
    ec[0] = ebc; es[0] = ebs; dc[0] = d1c; ds[0] = d1s;
    #pragma unroll
    for (int j = 1; j < 11; j++) {
        float pc = ec[j-1], ps = es[j-1];
        ec[j] = pc*ebc - ps*ebs;
        es[j] = ps*ebc + pc*ebs;
        pc = dc[j-1]; ps = ds[j-1];
        dc[j] = pc*d1c - ps*d1s;
        ds[j] = ps*d1c + pc*d1s;
    }
    float aRe[12], aIm[12];
    #pragma unroll
    for (int j = 0; j < 12; j++) { aRe[j] = 0.f; aIm[j] = 0.f; }

    #pragma unroll 4
    for (int t = 0; t < 32; t++) {
        float v = vbuf[(chunk*32 + t)*33 + c];
        aRe[0] += v;
        #pragma unroll
        for (int j = 1; j < 12; j++) {
            aRe[j] += v * ec[j-1];
            aIm[j] -= v * es[j-1];
            float pc = ec[j-1], ps = es[j-1];
            ec[j-1] = pc*dc[j-1] - ps*ds[j-1];
            es[j-1] = ps*dc[j-1] + pc*ds[j-1];
        }
    }
    {
        float* pp = part + w * 25;
        pp[0] = aRe[0]; pp[1] = 0.0f;
        #pragma unroll
        for (int j = 1; j < 12; j++) { pp[2*j] = aRe[j]; pp[2*j+1] = aIm[j]; }
    }
    __syncthreads();

    // Reduce 8 chunks, write A1[b][j][h][c][2]
    #pragma unroll
    for (int f0 = 0; f0 < 3; f0++) {
        int f = w + 256 * f0;
        int j = f >> 6, cc = (f >> 1) & 31, reim = f & 1;
        int jp = 2*j + reim;
        float s = 0.f;
        #pragma unroll
        for (int ch = 0; ch < 8; ch++) s += part[(ch*32 + cc)*25 + jp];
        A1[((size_t)(b*12 + j)*256 + h)*64 + cc*2 + reim] = s;
    }
}

// -------- Kernel C: h-DFT, spectral multiply, inverse h-DFT --------
// grid: B*12 blocks (one per (b, j-col)), 256 threads.
// Reads A1[b][j][h][c][2], writes T[b][h][j][o][2] (scaled by (2 or 1)/65536)
__global__ __launch_bounds__(256) void kernC(
    const float* __restrict__ A1,
    const float* __restrict__ k1r, const float* __restrict__ k1i,
    const float* __restrict__ k2r, const float* __restrict__ k2i,
    float* __restrict__ T)
{
    __shared__ float vft[NMODE * 64];  // [i][c][2]
    __shared__ float Sm[NMODE * 64];   // [i][o][2]
    __shared__ float ct[256], st[256];

    const int b = blockIdx.x / 12;
    const int j = blockIdx.x % 12;
    const int t = threadIdx.x;

    __sincosf(0.0245436926066f * (float)t, &st[t], &ct[t]);
    __syncthreads();

    const float* ag = A1 + (size_t)(b*12 + j) * 16384;
    const int c  = t & 31;
    const int i0 = t >> 5; // 0..7 ; handles modes i0, i0+8, i0+16

    // Stage 1: vft[i][c] = sum_h A1row[h][c] * e^{-2pi i ia h /256}
    {
        const int ia0 = i0;                               // 0..7  (<12)
        const int ia1 = (i0 + 8 < 12) ? (i0 + 8) : (232 + i0 + 8);
        const int ia2 = 232 + i0 + 16;                    // rows 244..255
        float r0=0,m0=0, r1=0,m1=0, r2=0,m2=0;
        #pragma unroll 4
        for (int hh = 0; hh < 256; hh++) {
            float2 av = *reinterpret_cast<const float2*>(ag + hh*64 + c*2);
            int p0 = (ia0*hh) & 255; float c0 = ct[p0], s0 = st[p0];
            int p1 = (ia1*hh) & 255; float c1 = ct[p1], s1 = st[p1];
            int p2 = (ia2*hh) & 255; float c2 = ct[p2], s2 = st[p2];
            r0 += av.x*c0 + av.y*s0;  m0 += av.y*c0 - av.x*s0;
            r1 += av.x*c1 + av.y*s1;  m1 += av.y*c1 - av.x*s1;
            r2 += av.x*c2 + av.y*s2;  m2 += av.y*c2 - av.x*s2;
        }
        vft[(i0      *32 + c)*2] = r0; vft[(i0      *32 + c)*2 + 1] = m0;
        vft[((i0+8 ) *32 + c)*2] = r1; vft[((i0+8 ) *32 + c)*2 + 1] = m1;
        vft[((i0+16) *32 + c)*2] = r2; vft[((i0+16) *32 + c)*2 + 1] = m2;
    }
    __syncthreads();

    // Stage 2: S[i][o] = sum_c vft[i][c] * (kr + i*ki)[c,o,ii,j]
    {
        const int o = t & 31;
        const float* wr0 = k1r;                  const float* wi0 = k1i;                  const int ii0 = i0;
        const float* wr1 = (i0+8 < 12) ? k1r : k2r;
        const float* wi1 = (i0+8 < 12) ? k1i : k2i;
        const int    ii1 = (i0+8 < 12) ? (i0+8) : (i0-4);
        const float* wr2 = k2r;                  const float* wi2 = k2i;                  const int ii2 = i0 + 4;
        float r0=0,m0=0, r1=0,m1=0, r2=0,m2=0;
        #pragma unroll
        for (int cc = 0; cc < 32; cc++) {
            float vr0 = vft[(i0      *32 + cc)*2], vi0 = vft[(i0      *32 + cc)*2 + 1];
            float vr1 = vft[((i0+8 ) *32 + cc)*2], vi1 = vft[((i0+8 ) *32 + cc)*2 + 1];
            float vr2 = vft[((i0+16) *32 + cc)*2], vi2 = vft[((i0+16) *32 + cc)*2 + 1];
            size_t base = (size_t)(cc*32 + o) * 144 + j;   // ((c*32+o)*12+ii)*12+j
            float kr0 = wr0[base + (size_t)ii0*12], ki0 = wi0[base + (size_t)ii0*12];
            float kr1 = wr1[base + (size_t)ii1*12], ki1 = wi1[base + (size_t)ii1*12];
            float kr2 = wr2[base + (size_t)ii2*12], ki2 = wi2[base + (size_t)ii2*12];
            r0 += vr0*kr0 - vi0*ki0;  m0 += vr0*ki0 + vi0*kr0;
            r1 += vr1*kr1 - vi1*ki1;  m1 += vr1*ki1 + vi1*kr1;
            r2 += vr2*kr2 - vi2*ki2;  m2 += vr2*ki2 + vi2*kr2;
        }
        Sm[(i0      *32 + o)*2] = r0; Sm[(i0      *32 + o)*2 + 1] = m0;
        Sm[((i0+8 ) *32 + o)*2] = r1; Sm[((i0+8 ) *32 + o)*2 + 1] = m1;
        Sm[((i0+16) *32 + o)*2] = r2; Sm[((i0+16) *32 + o)*2 + 1] = m2;
    }
    __syncthreads();

    // Stage 3: T[h=t][o] = sum_m S[m][o] * e^{+2pi i ia h/256}, fold scale
    {
        float Tre[32], Tim[32];
        #pragma unroll
        for (int o = 0; o < 32; o++) { Tre[o] = 0.f; Tim[o] = 0.f; }
        #pragma unroll 4
        for (int m = 0; m < 24; m++) {
            int iam = (m < 12) ? m : (232 + m);
            int ph = (iam * t) & 255;
            float cc2 = ct[ph], ss2 = st[ph];
            #pragma unroll
            for (int o = 0; o < 32; o++) {
                float sr = Sm[(m*32 + o)*2], si = Sm[(m*32 + o)*2 + 1];
                Tre[o] += sr*cc2 - si*ss2;
                Tim[o] += sr*ss2 + si*cc2;
            }
        }
        const float sc = (j == 0) ? (1.0f/65536.0f) : (2.0f/65536.0f);
        float* dst = T + (((size_t)b*256 + t)*12 + j)*64;
        #pragma unroll
        for (int o = 0; o < 32; o++) {
            dst[2*o]     = Tre[o] * sc;
            dst[2*o + 1] = Tim[o] * sc;
        }
    }
}

// -------- Kernel D: Fv reconstruction + G/u/Wu/Hu + born + out MLP --------
// grid: B*H blocks, 256 threads (one per w)
__global__ __launch_bounds__(256) void kernD(
    const float* __restrict__ x, const float* __restrict__ kk,
    const float* __restrict__ Gw1, const float* __restrict__ Gb1,
    const float* __restrict__ Gw2, const float* __restrict__ Gb2,
    const float* __restrict__ uw,  const float* __restrict__ ub,
    const float* __restrict__ Wuw, const float* __restrict__ Wub,
    const float* __restrict__ Huw, const float* __restrict__ Hub,
    const float* __restrict__ ow,  const float* __restrict__ ob,
    const float* __restrict__ T, float* __restrict__ out)
{
    __shared__ float Tl[768]; // [j][o][2]
    const int bh = blockIdx.x;
    const int w  = threadIdx.x;
    {
        const float* Ts = T + (size_t)bh * 768;
        Tl[w]       = Ts[w];
        Tl[w + 256] = Ts[w + 256];
        Tl[w + 512] = Ts[w + 512];
    }

    float kv[4];
    {
        const float4 t4 = *reinterpret_cast<const float4*>(kk + ((size_t)bh * 256 + w) * 4);
        kv[0] = t4.x; kv[1] = t4.y; kv[2] = t4.z; kv[3] = t4.w;
    }
    float xv[32];
    {
        const float4* xp = reinterpret_cast<const float4*>(x + ((size_t)bh * 256 + w) * 32);
        #pragma unroll
        for (int i = 0; i < 8; i++) {
            float4 t4 = xp[i];
            xv[4*i] = t4.x; xv[4*i+1] = t4.y; xv[4*i+2] = t4.z; xv[4*i+3] = t4.w;
        }
    }

    float G[32];
    {
        float hb[64];
        #pragma unroll
        for (int m = 0; m < 64; m++) {
            float a = Gb1[m] + kv[0]*Gw1[m] + kv[1]*Gw1[64+m] + kv[2]*Gw1[128+m] + kv[3]*Gw1[192+m];
            hb[m] = gelu_f(a);
        }
        #pragma unroll 4
        for (int o = 0; o < 32; o++) {
            float a = Gb2[o];
            #pragma unroll
            for (int m = 0; m < 64; m++) a += hb[m] * Gw2[m*32 + o];
            G[o] = a;
        }
    }
    float uu[32];
    #pragma unroll 4
    for (int o = 0; o < 32; o++) {
        float a = ub[o];
        #pragma unroll
        for (int c = 0; c < 32; c++) a += xv[c] * uw[c*32 + o];
        uu[o] = a;
    }
    float Wu[32], Hu[32];
    #pragma unroll 4
    for (int o = 0; o < 32; o++) {
        float a = Wub[o], bb2 = Hub[o];
        #pragma unroll
        for (int c = 0; c < 32; c++) {
            a   += uu[c] * Wuw[c*32 + o];
            bb2 += uu[c] * Huw[c*32 + o];
        }
        Wu[o] = a; Hu[o] = bb2;
    }
    __syncthreads();

    // Fv from 12 modes: Fv[o] = ReT0'[o] + sum_{j>=1} (cos*ReTj' - sin*ImTj')
    float born[32];
    #pragma unroll
    for (int o = 0; o < 32; o++) born[o] = Tl[o*2];
    {
        float e1s, e1c; __sincosf(0.0245436926066f * (float)w, &e1s, &e1c);
        float ec = e1c, es = e1s;
        #pragma unroll
        for (int j = 1; j < 12; j++) {
            #pragma unroll
            for (int o = 0; o < 32; o++)
                born[o] += ec * Tl[j*64 + o*2] - es * Tl[j*64 + o*2 + 1];
            float pc = ec, ps = es;
            ec = pc*e1c - ps*e1s;
            es = ps*e1c + pc*e1s;
        }
    }
    // born = Wu - G*(Hu - Fv)
    #pragma unroll
    for (int o = 0; o < 32; o++) born[o] = Wu[o] - G[o] * (Hu[o] - born[o]);

    // out = gelu(born @ ow + ob)
    float res[32];
    #pragma unroll 4
    for (int o = 0; o < 32; o++) {
        float a = ob[o];
        #pragma unroll
        for (int c = 0; c < 32; c++) a += born[c] * ow[c*32 + o];
        res[o] = gelu_f(a);
    }
    float* op = out + ((size_t)bh * 256 + w) * 32;
    #pragma unroll
    for (int i = 0; i < 8; i++)
        reinterpret_cast<float4*>(op)[i] = make_float4(res[4*i], res[4*i+1], res[4*i+2], res[4*i+3]);
}

extern "C" void kernel_launch(void* const* d_in, const int* in_sizes, int n_in,
                              void* d_out, int out_size, void* d_ws, size_t ws_size,
                              hipStream_t stream)
{
    const float* x   = (const float*)d_in[0];
    const float* kk  = (const float*)d_in[1];
    const float* Lw1 = (const float*)d_in[2];
    const float* Lb1 = (const float*)d_in[3];
    const float* Lw2 = (const float*)d_in[4];
    const float* Lb2 = (const float*)d_in[5];
    const float* Gw1 = (const float*)d_in[6];
    const float* Gb1 = (const float*)d_in[7];
    const float* Gw2 = (const float*)d_in[8];
    const float* Gb2 = (const float*)d_in[9];
    const float* uw  = (const float*)d_in[10];
    const float* ub  = (const float*)d_in[11];
    const float* Wuw = (const float*)d_in[12];
    const float* Wub = (const float*)d_in[13];
    const float* Huw = (const float*)d_in[14];
    const float* Hub = (const float*)d_in[15];
    const float* Msw = (const float*)d_in[16];
    const float* Msb = (const float*)d_in[17];
    const float* ow  = (const float*)d_in[18];
    const float* ob  = (const float*)d_in[19];
    const float* k1r = (const float*)d_in[20];
    const float* k1i = (const float*)d_in[21];
    const float* k2r = (const float*)d_in[22];
    const float* k2i = (const float*)d_in[23];

    float* A1 = (float*)d_ws;                // 8*12*256*64 = 1,572,864 floats
    float* T  = A1 + 1572864;                // 8*256*12*64 = 1,572,864 floats

    float* outp = (float*)d_out;

    kernA<<<BB*HH, 256, 0, stream>>>(x, kk, Lw1, Lb1, Lw2, Lb2, uw, ub, Msw, Msb, A1);
    kernC<<<BB*12, 256, 0, stream>>>(A1, k1r, k1i, k2r, k2i, T);
    kernD<<<BB*HH, 256, 0, stream>>>(x, kk, Gw1, Gb1, Gw2, Gb2, uw, ub,
                                     Wuw, Wub, Huw, Hub, ow, ob, T, outp);
}

// Round 2
// 214.153 us; speedup vs baseline: 1.8196x; 1.8196x over previous
//
#include <hip/hip_runtime.h>
#include <math.h>

#define BB 8
#define NM 12
#define NMODE 24

typedef __attribute__((ext_vector_type(8))) short bf16x8;
typedef __attribute__((ext_vector_type(4))) short bf16x4;
typedef __attribute__((ext_vector_type(4))) float f32x4;

#define MFMA(a,b,c) __builtin_amdgcn_mfma_f32_16x16x32_bf16(a,b,c,0,0,0)

__device__ __forceinline__ short f2b(float f){
    unsigned u = __builtin_bit_cast(unsigned, f);
    u = (u + 0x7FFFu + ((u >> 16) & 1u)) >> 16;
    return (short)u;
}
__device__ __forceinline__ float gelu_f(float v) {
    float u = 0.7978845608028654f * (v + 0.044715f * v * v * v);
    float e = __expf(2.0f * u);
    float t = 1.0f - 2.0f / (e + 1.0f);
    return 0.5f * v * (1.0f + t);
}

// ======== Kernel A: v = L*u + Ms (MFMA) + row-DFT over w (MFMA) ========
// block = one (b,h) row of 256 pixels; 256 threads = 4 waves.
__global__ __launch_bounds__(256, 2) void kernA(
    const float* __restrict__ x, const float* __restrict__ kk,
    const float* __restrict__ Lw1, const float* __restrict__ Lb1,
    const float* __restrict__ Lw2, const float* __restrict__ Lb2,
    const float* __restrict__ uw,  const float* __restrict__ ubv,
    const float* __restrict__ Msw, const float* __restrict__ Msb,
    float* __restrict__ A1)
{
    __shared__ short wL1T[64*40];   // Lw1^T padded K=32 (rows=hidden ch, cols=k-in)
    __shared__ short wL2T[32*72];   // Lw2^T (rows=out ch, cols=hidden 64)
    __shared__ short wuT [32*40];
    __shared__ short wMsT[32*40];
    __shared__ short hb  [256*72];  // hidden (gelu'd), pixels x 64
    __shared__ short vT  [32*264];  // v transposed: [c][w]

    const int bh = blockIdx.x, b = bh >> 8, h = bh & 255;
    const int tid = threadIdx.x;
    const int l = tid & 63, wv = tid >> 6, q = l >> 4, rr = l & 15;
    const float tp = 6.28318530717958648f / 256.0f;

    // ---- stage weights (transposed, bf16) ----
    for (int idx = tid; idx < 64*32; idx += 256){
        int o = idx >> 5, i = idx & 31;
        wL1T[o*40 + i] = (i < 4) ? f2b(Lw1[i*64 + o]) : (short)0;
    }
    for (int idx = tid; idx < 32*64; idx += 256){
        int o = idx >> 6, m = idx & 63;
        wL2T[o*72 + m] = f2b(Lw2[m*32 + o]);
    }
    for (int idx = tid; idx < 32*32; idx += 256){
        int o = idx >> 5, c = idx & 31;
        wuT [o*40 + c] = f2b(uw[c*32 + o]);
        wMsT[o*40 + c] = (c < 4) ? f2b(Msw[c*32 + o]) : (short)0;
    }
    __syncthreads();

    // ---- b-fragments (weights) ----
    bf16x8 bu[2], bms[2], bh1[4];
    #pragma unroll
    for (int nt = 0; nt < 2; nt++){
        bu [nt] = *(const bf16x8*)(wuT  + (rr + 16*nt)*40 + q*8);
        bms[nt] = *(const bf16x8*)(wMsT + (rr + 16*nt)*40 + q*8);
    }
    #pragma unroll
    for (int nt = 0; nt < 4; nt++)
        bh1[nt] = *(const bf16x8*)(wL1T + (rr + 16*nt)*40 + q*8);

    f32x4 accU[4][2], accH[4][4], accM[4][2];
    #pragma unroll
    for (int mt = 0; mt < 4; mt++){
        #pragma unroll
        for (int nt = 0; nt < 2; nt++){ accU[mt][nt] = (f32x4){0.f,0.f,0.f,0.f}; accM[mt][nt] = (f32x4){0.f,0.f,0.f,0.f}; }
        #pragma unroll
        for (int nt = 0; nt < 4; nt++) accH[mt][nt] = (f32x4){0.f,0.f,0.f,0.f};
    }

    // ---- u = x@uw ; hid = k@Lw1 ; Ms = k@Msw  (A-operands direct from global) ----
    #pragma unroll
    for (int mt = 0; mt < 4; mt++){
        int m = wv*64 + mt*16 + rr;
        const float* xrow = x + ((size_t)bh*256 + m)*32 + q*8;
        float4 x0 = *(const float4*)xrow;
        float4 x1 = *(const float4*)(xrow + 4);
        bf16x8 ax;
        ax[0]=f2b(x0.x); ax[1]=f2b(x0.y); ax[2]=f2b(x0.z); ax[3]=f2b(x0.w);
        ax[4]=f2b(x1.x); ax[5]=f2b(x1.y); ax[6]=f2b(x1.z); ax[7]=f2b(x1.w);
        bf16x8 ak = {0,0,0,0,0,0,0,0};
        if (q == 0){
            float4 k4 = *(const float4*)(kk + ((size_t)bh*256 + m)*4);
            ak[0]=f2b(k4.x); ak[1]=f2b(k4.y); ak[2]=f2b(k4.z); ak[3]=f2b(k4.w);
        }
        #pragma unroll
        for (int nt = 0; nt < 2; nt++) accU[mt][nt] = MFMA(ax, bu[nt], accU[mt][nt]);
        #pragma unroll
        for (int nt = 0; nt < 4; nt++) accH[mt][nt] = MFMA(ak, bh1[nt], accH[mt][nt]);
        #pragma unroll
        for (int nt = 0; nt < 2; nt++) accM[mt][nt] = MFMA(ak, bms[nt], accM[mt][nt]);
    }
    // gelu hidden (+bias) -> hb
    #pragma unroll
    for (int nt = 0; nt < 4; nt++){
        float bias = Lb1[rr + 16*nt];
        #pragma unroll
        for (int mt = 0; mt < 4; mt++)
            #pragma unroll
            for (int rg = 0; rg < 4; rg++)
                hb[(wv*64 + mt*16 + 4*q + rg)*72 + rr + 16*nt] = f2b(gelu_f(accH[mt][nt][rg] + bias));
    }
    __syncthreads();

    // ---- L = hid @ Lw2 ; v = (L+b)*(u+b) + (Ms+b) ; store vT ----
    bf16x8 bl2[2][2];
    #pragma unroll
    for (int nt = 0; nt < 2; nt++)
        #pragma unroll
        for (int ks = 0; ks < 2; ks++)
            bl2[nt][ks] = *(const bf16x8*)(wL2T + (rr + 16*nt)*72 + ks*32 + q*8);

    #pragma unroll
    for (int mt = 0; mt < 4; mt++){
        f32x4 accL[2];
        #pragma unroll
        for (int nt = 0; nt < 2; nt++) accL[nt] = (f32x4){0.f,0.f,0.f,0.f};
        #pragma unroll
        for (int ks = 0; ks < 2; ks++){
            bf16x8 ah = *(const bf16x8*)(hb + (wv*64 + mt*16 + rr)*72 + ks*32 + q*8);
            #pragma unroll
            for (int nt = 0; nt < 2; nt++) accL[nt] = MFMA(ah, bl2[nt][ks], accL[nt]);
        }
        #pragma unroll
        for (int nt = 0; nt < 2; nt++){
            float Lb = Lb2[rr + 16*nt], ub0 = ubv[rr + 16*nt], mb = Msb[rr + 16*nt];
            bf16x4 pack;
            #pragma unroll
            for (int rg = 0; rg < 4; rg++){
                float v = (accL[nt][rg] + Lb) * (accU[mt][nt][rg] + ub0) + accM[mt][nt][rg] + mb;
                pack[rg] = f2b(v);
            }
            *(bf16x4*)(vT + (rr + 16*nt)*264 + wv*64 + mt*16 + 4*q) = pack;
        }
    }
    __syncthreads();

    // ---- row-DFT: D[r][c] = sum_w basis[r][w] * v[w][c] ----
    // basis rows: r<12 -> cos(2pi r w/256); 12<=r<24 -> sin(2pi (r-12) w/256); else 0
    const int mt2 = wv >> 1, nt2 = wv & 1;
    const int rowr = rr + 16*mt2;
    const int jp   = (rowr < 12) ? rowr : rowr - 12;
    const bool isSin = (rowr >= 12);
    const bool dead  = (rowr >= 24);
    float stc, ctc; __sincosf(tp * (float)jp, &stc, &ctc);
    f32x4 accD = (f32x4){0.f,0.f,0.f,0.f};
    #pragma unroll
    for (int ks = 0; ks < 8; ks++){
        bf16x8 av = {0,0,0,0,0,0,0,0};
        if (!dead){
            int w0 = ks*32 + q*8;
            int p0 = (jp * w0) & 255;
            float s, c; __sincosf(tp * (float)p0, &s, &c);
            #pragma unroll
            for (int e = 0; e < 8; e++){
                av[e] = f2b(isSin ? s : c);
                float c2 = c*ctc - s*stc;
                float s2 = s*ctc + c*stc;
                c = c2; s = s2;
            }
        }
        bf16x8 bv = *(const bf16x8*)(vT + (rr + 16*nt2)*264 + ks*32 + q*8);
        accD = MFMA(av, bv, accD);
    }
    #pragma unroll
    for (int rg = 0; rg < 4; rg++){
        int m = mt2*16 + 4*q + rg;
        int c = rr + 16*nt2;
        if (m < 12)
            A1[(((size_t)(b*12 + m))*256 + h)*64 + c*2]     = accD[rg];
        else if (m < 24)
            A1[(((size_t)(b*12 + (m-12)))*256 + h)*64 + c*2 + 1] = -accD[rg];
    }
}

// ======== Kernel C: h-DFT, spectral multiply, inverse h-DFT (unchanged) ========
__global__ __launch_bounds__(256) void kernC(
    const float* __restrict__ A1,
    const float* __restrict__ k1r, const float* __restrict__ k1i,
    const float* __restrict__ k2r, const float* __restrict__ k2i,
    float* __restrict__ T)
{
    __shared__ float vft[NMODE * 64];
    __shared__ float Sm[NMODE * 64];
    __shared__ float ct[256], st[256];

    const int b = blockIdx.x / 12;
    const int j = blockIdx.x % 12;
    const int t = threadIdx.x;

    __sincosf(0.0245436926066f * (float)t, &st[t], &ct[t]);
    __syncthreads();

    const float* ag = A1 + (size_t)(b*12 + j) * 16384;
    const int c  = t & 31;
    const int i0 = t >> 5;

    {
        const int ia0 = i0;
        const int ia1 = (i0 + 8 < 12) ? (i0 + 8) : (232 + i0 + 8);
        const int ia2 = 232 + i0 + 16;
        float r0=0,m0=0, r1=0,m1=0, r2=0,m2=0;
        #pragma unroll 4
        for (int hh = 0; hh < 256; hh++) {
            float2 av = *reinterpret_cast<const float2*>(ag + hh*64 + c*2);
            int p0 = (ia0*hh) & 255; float c0 = ct[p0], s0 = st[p0];
            int p1 = (ia1*hh) & 255; float c1 = ct[p1], s1 = st[p1];
            int p2 = (ia2*hh) & 255; float c2 = ct[p2], s2 = st[p2];
            r0 += av.x*c0 + av.y*s0;  m0 += av.y*c0 - av.x*s0;
            r1 += av.x*c1 + av.y*s1;  m1 += av.y*c1 - av.x*s1;
            r2 += av.x*c2 + av.y*s2;  m2 += av.y*c2 - av.x*s2;
        }
        vft[(i0      *32 + c)*2] = r0; vft[(i0      *32 + c)*2 + 1] = m0;
        vft[((i0+8 ) *32 + c)*2] = r1; vft[((i0+8 ) *32 + c)*2 + 1] = m1;
        vft[((i0+16) *32 + c)*2] = r2; vft[((i0+16) *32 + c)*2 + 1] = m2;
    }
    __syncthreads();

    {
        const int o = t & 31;
        const float* wr0 = k1r;                  const float* wi0 = k1i;                  const int ii0 = i0;
        const float* wr1 = (i0+8 < 12) ? k1r : k2r;
        const float* wi1 = (i0+8 < 12) ? k1i : k2i;
        const int    ii1 = (i0+8 < 12) ? (i0+8) : (i0-4);
        const float* wr2 = k2r;                  const float* wi2 = k2i;                  const int ii2 = i0 + 4;
        float r0=0,m0=0, r1=0,m1=0, r2=0,m2=0;
        #pragma unroll
        for (int cc = 0; cc < 32; cc++) {
            float vr0 = vft[(i0      *32 + cc)*2], vi0 = vft[(i0      *32 + cc)*2 + 1];
            float vr1 = vft[((i0+8 ) *32 + cc)*2], vi1 = vft[((i0+8 ) *32 + cc)*2 + 1];
            float vr2 = vft[((i0+16) *32 + cc)*2], vi2 = vft[((i0+16) *32 + cc)*2 + 1];
            size_t base = (size_t)(cc*32 + o) * 144 + j;
            float kr0 = wr0[base + (size_t)ii0*12], ki0 = wi0[base + (size_t)ii0*12];
            float kr1 = wr1[base + (size_t)ii1*12], ki1 = wi1[base + (size_t)ii1*12];
            float kr2 = wr2[base + (size_t)ii2*12], ki2 = wi2[base + (size_t)ii2*12];
            r0 += vr0*kr0 - vi0*ki0;  m0 += vr0*ki0 + vi0*kr0;
            r1 += vr1*kr1 - vi1*ki1;  m1 += vr1*ki1 + vi1*kr1;
            r2 += vr2*kr2 - vi2*ki2;  m2 += vr2*ki2 + vi2*kr2;
        }
        Sm[(i0      *32 + o)*2] = r0; Sm[(i0      *32 + o)*2 + 1] = m0;
        Sm[((i0+8 ) *32 + o)*2] = r1; Sm[((i0+8 ) *32 + o)*2 + 1] = m1;
        Sm[((i0+16) *32 + o)*2] = r2; Sm[((i0+16) *32 + o)*2 + 1] = m2;
    }
    __syncthreads();

    {
        float Tre[32], Tim[32];
        #pragma unroll
        for (int o = 0; o < 32; o++) { Tre[o] = 0.f; Tim[o] = 0.f; }
        #pragma unroll 4
        for (int m = 0; m < 24; m++) {
            int iam = (m < 12) ? m : (232 + m);
            int ph = (iam * t) & 255;
            float cc2 = ct[ph], ss2 = st[ph];
            #pragma unroll
            for (int o = 0; o < 32; o++) {
                float sr = Sm[(m*32 + o)*2], si = Sm[(m*32 + o)*2 + 1];
                Tre[o] += sr*cc2 - si*ss2;
                Tim[o] += sr*ss2 + si*cc2;
            }
        }
        const float sc = (j == 0) ? (1.0f/65536.0f) : (2.0f/65536.0f);
        float* dst = T + (((size_t)b*256 + t)*12 + j)*64;
        #pragma unroll
        for (int o = 0; o < 32; o++) {
            dst[2*o]     = Tre[o] * sc;
            dst[2*o + 1] = Tim[o] * sc;
        }
    }
}

// ======== Kernel D: G/u/Wu/Hu + Fv (MFMA inverse w-DFT) + born + out MLP ========
__global__ __launch_bounds__(256, 2) void kernD(
    const float* __restrict__ x, const float* __restrict__ kk,
    const float* __restrict__ Gw1, const float* __restrict__ Gb1,
    const float* __restrict__ Gw2, const float* __restrict__ Gb2,
    const float* __restrict__ uw,  const float* __restrict__ ubv,
    const float* __restrict__ Wuw, const float* __restrict__ Wub,
    const float* __restrict__ Huw, const float* __restrict__ Hub,
    const float* __restrict__ ow,  const float* __restrict__ ob,
    const float* __restrict__ T, float* __restrict__ out)
{
    __shared__ short GT1[64*40], GT2[32*72];
    __shared__ short uwT[32*40], WuT[32*40], HuT[32*40], owT[32*40], TmT[32*40];
    __shared__ short hb[256*72];
    __shared__ short ub[256*40];
    short* bornb = hb;   // reuse (barrier-separated)

    const int bh = blockIdx.x;
    const int tid = threadIdx.x;
    const int l = tid & 63, wv = tid >> 6, q = l >> 4, rr = l & 15;
    const float tp = 6.28318530717958648f / 256.0f;

    // ---- stage weights + T-tile ----
    for (int idx = tid; idx < 64*32; idx += 256){
        int o = idx >> 5, i = idx & 31;
        GT1[o*40 + i] = (i < 4) ? f2b(Gw1[i*64 + o]) : (short)0;
    }
    for (int idx = tid; idx < 32*64; idx += 256){
        int o = idx >> 6, m = idx & 63;
        GT2[o*72 + m] = f2b(Gw2[m*32 + o]);
    }
    for (int idx = tid; idx < 32*32; idx += 256){
        int o = idx >> 5, c = idx & 31;
        uwT[o*40 + c] = f2b(uw [c*32 + o]);
        WuT[o*40 + c] = f2b(Wuw[c*32 + o]);
        HuT[o*40 + c] = f2b(Huw[c*32 + o]);
        owT[o*40 + c] = f2b(ow [c*32 + o]);
    }
    for (int idx = tid; idx < 768; idx += 256){
        int j = idx >> 6, rem = idx & 63, o = rem >> 1, reim = rem & 1;
        TmT[o*40 + 2*j + reim] = f2b(T[(size_t)bh*768 + idx]);
    }
    { int o = tid >> 3, e = tid & 7; TmT[o*40 + 24 + e] = 0; }  // zero K-pad 24..31
    __syncthreads();

    // ---- u & hidden(G) ----
    bf16x8 bg1[4], bu2[2];
    #pragma unroll
    for (int nt = 0; nt < 4; nt++) bg1[nt] = *(const bf16x8*)(GT1 + (rr + 16*nt)*40 + q*8);
    #pragma unroll
    for (int nt = 0; nt < 2; nt++) bu2[nt] = *(const bf16x8*)(uwT + (rr + 16*nt)*40 + q*8);

    f32x4 accU[4][2], accH[4][4];
    #pragma unroll
    for (int mt = 0; mt < 4; mt++){
        #pragma unroll
        for (int nt = 0; nt < 2; nt++) accU[mt][nt] = (f32x4){0.f,0.f,0.f,0.f};
        #pragma unroll
        for (int nt = 0; nt < 4; nt++) accH[mt][nt] = (f32x4){0.f,0.f,0.f,0.f};
    }
    #pragma unroll
    for (int mt = 0; mt < 4; mt++){
        int m = wv*64 + mt*16 + rr;
        const float* xrow = x + ((size_t)bh*256 + m)*32 + q*8;
        float4 x0 = *(const float4*)xrow;
        float4 x1 = *(const float4*)(xrow + 4);
        bf16x8 ax;
        ax[0]=f2b(x0.x); ax[1]=f2b(x0.y); ax[2]=f2b(x0.z); ax[3]=f2b(x0.w);
        ax[4]=f2b(x1.x); ax[5]=f2b(x1.y); ax[6]=f2b(x1.z); ax[7]=f2b(x1.w);
        bf16x8 ak = {0,0,0,0,0,0,0,0};
        if (q == 0){
            float4 k4 = *(const float4*)(kk + ((size_t)bh*256 + m)*4);
            ak[0]=f2b(k4.x); ak[1]=f2b(k4.y); ak[2]=f2b(k4.z); ak[3]=f2b(k4.w);
        }
        #pragma unroll
        for (int nt = 0; nt < 2; nt++) accU[mt][nt] = MFMA(ax, bu2[nt], accU[mt][nt]);
        #pragma unroll
        for (int nt = 0; nt < 4; nt++) accH[mt][nt] = MFMA(ak, bg1[nt], accH[mt][nt]);
    }
    #pragma unroll
    for (int nt = 0; nt < 4; nt++){
        float bias = Gb1[rr + 16*nt];
        #pragma unroll
        for (int mt = 0; mt < 4; mt++)
            #pragma unroll
            for (int rg = 0; rg < 4; rg++)
                hb[(wv*64 + mt*16 + 4*q + rg)*72 + rr + 16*nt] = f2b(gelu_f(accH[mt][nt][rg] + bias));
    }
    #pragma unroll
    for (int nt = 0; nt < 2; nt++){
        float bias = ubv[rr + 16*nt];
        #pragma unroll
        for (int mt = 0; mt < 4; mt++)
            #pragma unroll
            for (int rg = 0; rg < 4; rg++)
                ub[(wv*64 + mt*16 + 4*q + rg)*40 + rr + 16*nt] = f2b(accU[mt][nt][rg] + bias);
    }
    __syncthreads();

    // ---- G = hid@Gw2 ; Wu,Hu = u@{Wuw,Huw} ; Fv = basis2 @ Tm ----
    bf16x8 bg2[2][2], bw[2], bhh[2], bt[2];
    #pragma unroll
    for (int nt = 0; nt < 2; nt++){
        #pragma unroll
        for (int ks = 0; ks < 2; ks++)
            bg2[nt][ks] = *(const bf16x8*)(GT2 + (rr + 16*nt)*72 + ks*32 + q*8);
        bw [nt] = *(const bf16x8*)(WuT + (rr + 16*nt)*40 + q*8);
        bhh[nt] = *(const bf16x8*)(HuT + (rr + 16*nt)*40 + q*8);
        bt [nt] = *(const bf16x8*)(TmT + (rr + 16*nt)*40 + q*8);
    }
    f32x4 accG[4][2], accW[4][2], accHu[4][2], accF[4][2];
    #pragma unroll
    for (int mt = 0; mt < 4; mt++)
        #pragma unroll
        for (int nt = 0; nt < 2; nt++){
            accG[mt][nt] = (f32x4){0.f,0.f,0.f,0.f};  accW[mt][nt] = (f32x4){0.f,0.f,0.f,0.f};
            accHu[mt][nt] = (f32x4){0.f,0.f,0.f,0.f}; accF[mt][nt] = (f32x4){0.f,0.f,0.f,0.f};
        }
    #pragma unroll
    for (int mt = 0; mt < 4; mt++){
        #pragma unroll
        for (int ks = 0; ks < 2; ks++){
            bf16x8 ah = *(const bf16x8*)(hb + (wv*64 + mt*16 + rr)*72 + ks*32 + q*8);
            #pragma unroll
            for (int nt = 0; nt < 2; nt++) accG[mt][nt] = MFMA(ah, bg2[nt][ks], accG[mt][nt]);
        }
        bf16x8 au = *(const bf16x8*)(ub + (wv*64 + mt*16 + rr)*40 + q*8);
        #pragma unroll
        for (int nt = 0; nt < 2; nt++){
            accW [mt][nt] = MFMA(au, bw [nt], accW [mt][nt]);
            accHu[mt][nt] = MFMA(au, bhh[nt], accHu[mt][nt]);
        }
        // basis2 A-frag: A[w][2j]=cos(2pi j w/256), A[w][2j+1]=-sin; K-cols 24..31 zero
        bf16x8 aF = {0,0,0,0,0,0,0,0};
        if (q < 3){
            int wpix = wv*64 + mt*16 + rr;
            int p0 = ((4*q) * wpix) & 255;
            float s, c;  __sincosf(tp * (float)p0, &s, &c);
            float ss, cs; __sincosf(tp * (float)wpix, &ss, &cs);
            #pragma unroll
            for (int pr = 0; pr < 4; pr++){
                aF[2*pr]   = f2b(c);
                aF[2*pr+1] = f2b(-s);
                float c2 = c*cs - s*ss;
                float s2 = s*cs + c*ss;
                c = c2; s = s2;
            }
        }
        #pragma unroll
        for (int nt = 0; nt < 2; nt++) accF[mt][nt] = MFMA(aF, bt[nt], accF[mt][nt]);
    }
    __syncthreads();

    // ---- born = Wu - G*(Hu - Fv) -> bornb ----
    #pragma unroll
    for (int nt = 0; nt < 2; nt++){
        float gb = Gb2[rr + 16*nt], wub = Wub[rr + 16*nt], hub = Hub[rr + 16*nt];
        #pragma unroll
        for (int mt = 0; mt < 4; mt++)
            #pragma unroll
            for (int rg = 0; rg < 4; rg++){
                float born = (accW[mt][nt][rg] + wub)
                           - (accG[mt][nt][rg] + gb) * ((accHu[mt][nt][rg] + hub) - accF[mt][nt][rg]);
                bornb[(wv*64 + mt*16 + 4*q + rg)*40 + rr + 16*nt] = f2b(born);
            }
    }
    __syncthreads();

    // ---- out = gelu(born@ow + ob) ----
    bf16x8 bo[2];
    #pragma unroll
    for (int nt = 0; nt < 2; nt++) bo[nt] = *(const bf16x8*)(owT + (rr + 16*nt)*40 + q*8);
    #pragma unroll
    for (int mt = 0; mt < 4; mt++){
        bf16x8 ab = *(const bf16x8*)(bornb + (wv*64 + mt*16 + rr)*40 + q*8);
        f32x4 acc[2];
        #pragma unroll
        for (int nt = 0; nt < 2; nt++) acc[nt] = (f32x4){0.f,0.f,0.f,0.f};
        #pragma unroll
        for (int nt = 0; nt < 2; nt++) acc[nt] = MFMA(ab, bo[nt], acc[nt]);
        #pragma unroll
        for (int nt = 0; nt < 2; nt++){
            float bias = ob[rr + 16*nt];
            #pragma unroll
            for (int rg = 0; rg < 4; rg++)
                out[((size_t)bh*256 + (wv*64 + mt*16 + 4*q + rg))*32 + rr + 16*nt]
                    = gelu_f(acc[nt][rg] + bias);
        }
    }
}

extern "C" void kernel_launch(void* const* d_in, const int* in_sizes, int n_in,
                              void* d_out, int out_size, void* d_ws, size_t ws_size,
                              hipStream_t stream)
{
    const float* x   = (const float*)d_in[0];
    const float* kk  = (const float*)d_in[1];
    const float* Lw1 = (const float*)d_in[2];
    const float* Lb1 = (const float*)d_in[3];
    const float* Lw2 = (const float*)d_in[4];
    const float* Lb2 = (const float*)d_in[5];
    const float* Gw1 = (const float*)d_in[6];
    const float* Gb1 = (const float*)d_in[7];
    const float* Gw2 = (const float*)d_in[8];
    const float* Gb2 = (const float*)d_in[9];
    const float* uw  = (const float*)d_in[10];
    const float* ub  = (const float*)d_in[11];
    const float* Wuw = (const float*)d_in[12];
    const float* Wub = (const float*)d_in[13];
    const float* Huw = (const float*)d_in[14];
    const float* Hub = (const float*)d_in[15];
    const float* Msw = (const float*)d_in[16];
    const float* Msb = (const float*)d_in[17];
    const float* ow  = (const float*)d_in[18];
    const float* ob  = (const float*)d_in[19];
    const float* k1r = (const float*)d_in[20];
    const float* k1i = (const float*)d_in[21];
    const float* k2r = (const float*)d_in[22];
    const float* k2i = (const float*)d_in[23];

    float* A1 = (float*)d_ws;                // 8*12*256*64 floats
    float* T  = A1 + 1572864;                // 8*256*12*64 floats
    float* outp = (float*)d_out;

    kernA<<<BB*256, 256, 0, stream>>>(x, kk, Lw1, Lb1, Lw2, Lb2, uw, ub, Msw, Msb, A1);
    kernC<<<BB*12, 256, 0, stream>>>(A1, k1r, k1i, k2r, k2i, T);
    kernD<<<BB*256, 256, 0, stream>>>(x, kk, Gw1, Gb1, Gw2, Gb2, uw, ub,
                                      Wuw, Wub, Huw, Hub, ow, ob, T, outp);
}